// Round 14
// baseline (65.800 us; speedup 1.0000x reference)
//
#include <hip/hip_runtime.h>

typedef __attribute__((ext_vector_type(8))) __bf16 bf16x8;
typedef __attribute__((ext_vector_type(4))) __bf16 bf16x4;
typedef __attribute__((ext_vector_type(2))) __bf16 bf16x2;
typedef __attribute__((ext_vector_type(4))) float f32x4;

#define LOG2E 1.44269504088896f
#define KSWZ(t) (((t) & 7) << 4)
#define VSWZ(d) ((((d) & 7) ^ (((d) >> 3) & 7)) << 4)

// 28 instances of dilated causal attention, each L=2048, d=64.
// q/k/v: (1, 8192, 12, 64) fp32 -> elem = tok*768 + head*64 + d.
// PARTIAL: QBLK=128 (8 waves x 16 q-rows), qt in 0..15, nkt = 2qt+2 KV
// tiles of 64. R14 decomposition: qt<8 DIRECT single blocks (2..16 tiles,
// longest launched first); qt 8..11 -> 3 chunks, qt 12..15 -> 4 chunks of
// <=8 tiles. 36 units/inst -> 1008 blocks, XCD-chunked (1008 = 8*126).
// u (reversed): 35..32 -> qt7..4 direct; 31..16 -> qt=12+(u-16)/4,
// c=(u-16)%4; 15..4 -> qt=8+(u-4)/3, c=(u-4)%3; 3..0 -> qt=u direct.
// Wave-specialized staging (w0-3: K, w4-7: V^T), swapped QK^T, in-register
// softmax, defer-max THR=8, DEFERRED l-reduce (epilogue only — per-tile
// cross-lane sum removed; rescale's row-uniform sc is per-lane safe).
// HARD CONSTRAINTS: VGPR <= 64 (R10); decode/nkt/mask/slot formulas are
// ONE COUPLED UNIT (R11 crash).
// Two kernels, NO device fences (R7: in-kernel cross-XCD fences ~7x stall).
// Zero-rows for non-dilated tokens fused into epilogues (no memset).
// ws slot (17408 B): O[128][64] bf16 + m[128] f32 + l[128] f32.
// slot = inst*28 + b + c,  b = (qt<12) ? (qt-8)*3 : 12+(qt-12)*4.

__device__ __forceinline__ void inst_decode(int inst, int& head, int& sstart,
                                            int& r, int& off)
{
    if (inst < 16)      { head = inst & 3;          sstart = (inst >> 2) * 2048; r = 1; off = 0; }
    else if (inst < 24) { int j = inst - 16; head = 4 + (j & 3); sstart = (j >> 2) * 4096; r = 2; off = 1; }
    else                { head = 8 + (inst - 24);   sstart = 0;                  r = 4; off = 2; }
}

__global__ __launch_bounds__(512)
void dilattn_partial(const float* __restrict__ Qg, const float* __restrict__ Kg,
                     const float* __restrict__ Vg, float* __restrict__ Og,
                     char* __restrict__ ws, const int* __restrict__ causal_p)
{
    const int bid  = blockIdx.x;
    const int unit = (bid & 7) * 126 + (bid >> 3);   // XCD-contiguous units
    const int inst = unit / 36;
    const int u    = 35 - (unit % 36);               // heavy blocks first
    int head, sstart, r, off;
    inst_decode(inst, head, sstart, r, off);

    const int causal = *causal_p;
    int qt, c, kt_begin, kt_end;
    bool direct;
    if (causal) {
        if (u >= 32)      { qt = 39 - u; c = 0; }          // 35..32 -> qt 4..7? no: 39-35=4
        else if (u >= 16) { qt = 12 + ((u - 16) >> 2); c = (u - 16) & 3; }
        else if (u >= 4)  { int t = u - 4; int q3 = t / 3; qt = 8 + q3; c = t - 3 * q3; }
        else              { qt = u; c = 0; }
        // NOTE: u=35 -> qt=4? That inverts heavy-first. Fix: qt = u - 28 for u>=32
        if (u >= 32) qt = u - 28;                          // 32..35 -> qt 4..7 (35 = qt7, first)
        int nkt = 2 * qt + 2;
        direct = (qt < 8);
        if (direct) { kt_begin = 0; kt_end = nkt; }
        else {
            kt_begin = c * 8;
            kt_end   = (kt_begin + 8 < nkt) ? kt_begin + 8 : nkt;
        }
    } else {
        if (u >= 16) return;                   // 16 q-tiles, one full block each
        qt = u; c = 0;
        kt_begin = 0; kt_end = 32; direct = true;
    }

    const int tid  = threadIdx.x;
    const int lane = tid & 63;
    const int wave = tid >> 6;                 // 0..7
    const int l15  = lane & 15;
    const int lhi  = lane >> 4;

    __shared__ char KV[16384];                 // K 8K | V^T 8K (single buffer)
    __shared__ __bf16 P_lds[8][16 * 64];       // per-wave P bridge (swizzled)

    // ---- Q fragments (scale * log2e folded in); serves as MFMA B ----
    const int qrow_base = qt * 128 + wave * 16;
    const float qscale = 0.125f * LOG2E;
    bf16x8 qfrag[2];
    {
        int qr = qrow_base + l15;
        long qtok = sstart + off + (long)r * qr;
        const float* qp = Qg + qtok * 768 + head * 64 + lhi * 8;
#pragma unroll
        for (int dc = 0; dc < 2; dc++) {
            f32x4 a = *(const f32x4*)(qp + dc * 32);
            f32x4 b = *(const f32x4*)(qp + dc * 32 + 4);
#pragma unroll
            for (int j = 0; j < 4; j++) {
                qfrag[dc][j]     = (__bf16)(a[j] * qscale);
                qfrag[dc][4 + j] = (__bf16)(b[j] * qscale);
            }
        }
    }

    f32x4 acc[4] = {};                          // O: row q=lhi*4+reg, col d=dt*16+l15
    float m_run = -INFINITY;                    // per-lane: q = l15
    float l_run = 0.f;                          // per-lane PARTIAL (reduced at end)

    // ---- wave-specialized staging roles ----
    const bool isK = (wave < 4);
    const int t2   = tid & 255;
    const int tokK = t2 >> 2, q4 = t2 & 3;          // K: (token, d-quarter)
    const int tokP = t2 >> 3, d8 = (t2 & 7) * 8;    // V: (token-pair, 8 d)

    f32x4 r0, r1, r2, r3;                       // staging regs (next tile)

    // ---- strength-reduced staging pointer: advance by one tile-stride ----
    const long gstep = (long)r * 64 * 768;      // floats per KV tile step
    const long vrow  = (long)r * 768;           // one dilated token (floats)
    const float* gp0;
    {
        long tb = sstart + off + (long)r * (kt_begin * 64);
        gp0 = isK ? (Kg + (tb + (long)r * tokK) * 768 + head * 64 + q4 * 16)
                  : (Vg + (tb + (long)r * 2 * tokP) * 768 + head * 64 + d8);
    }

#define LOAD_STEP() do {                                                       \
        if (isK) {                                                             \
            r0 = *(const f32x4*)(gp0);      r1 = *(const f32x4*)(gp0 + 4);     \
            r2 = *(const f32x4*)(gp0 + 8);  r3 = *(const f32x4*)(gp0 + 12);    \
        } else {                                                               \
            const float* g1_ = gp0 + vrow;                                     \
            r0 = *(const f32x4*)(gp0);      r1 = *(const f32x4*)(gp0 + 4);     \
            r2 = *(const f32x4*)(g1_);      r3 = *(const f32x4*)(g1_ + 4);     \
        }                                                                      \
        gp0 += gstep;                                                          \
    } while (0)

#define STORE_TILE() do {                                                      \
        if (isK) {                                                             \
            char* Kb_ = KV;                                                    \
            bf16x8 w0_, w1_;                                                   \
            _Pragma("unroll")                                                  \
            for (int j = 0; j < 4; j++) {                                      \
                w0_[j] = (__bf16)r0[j]; w0_[4 + j] = (__bf16)r1[j];            \
                w1_[j] = (__bf16)r2[j]; w1_[4 + j] = (__bf16)r3[j];            \
            }                                                                  \
            int kb_ = tokK * 128 + q4 * 32;                                    \
            *(bf16x8*)(Kb_ + ((kb_)      ^ KSWZ(tokK))) = w0_;                 \
            *(bf16x8*)(Kb_ + ((kb_ + 16) ^ KSWZ(tokK))) = w1_;                 \
        } else {                                                               \
            char* Vb_ = KV + 8192;                                             \
            _Pragma("unroll")                                                  \
            for (int j = 0; j < 4; j++) {                                      \
                int d_ = d8 + j;                                               \
                bf16x2 wa_; wa_[0] = (__bf16)r0[j]; wa_[1] = (__bf16)r2[j];    \
                *(bf16x2*)(Vb_ + ((d_ * 128 + tokP * 4) ^ VSWZ(d_))) = wa_;    \
                int d2_ = d8 + 4 + j;                                          \
                bf16x2 wb_; wb_[0] = (__bf16)r1[j]; wb_[1] = (__bf16)r3[j];    \
                *(bf16x2*)(Vb_ + ((d2_ * 128 + tokP * 4) ^ VSWZ(d2_))) = wb_;  \
            }                                                                  \
        }                                                                      \
    } while (0)

    // ---- prologue: stage first tile ----
    LOAD_STEP();
    STORE_TILE();
    __syncthreads();

    for (int kt = kt_begin; kt < kt_end; kt++) {
        const bool pf = (kt + 1 < kt_end);
        if (pf) LOAD_STEP();                   // tile kt+1; lands under compute

        char* Kb = KV;
        char* Vb = KV + 8192;

        // ---- S' = K Q^T : lane owns q = l15; regs (nt,reg) = k values ----
        f32x4 s[4];
        __builtin_amdgcn_s_setprio(1);
#pragma unroll
        for (int nt = 0; nt < 4; nt++) {
            f32x4 cc = {};
#pragma unroll
            for (int dc = 0; dc < 2; dc++) {
                int krow = nt * 16 + l15;
                const bf16x8 kf = *(const bf16x8*)(Kb +
                    ((krow * 128 + dc * 64 + lhi * 16) ^ KSWZ(krow)));
                cc = __builtin_amdgcn_mfma_f32_16x16x32_bf16(kf, qfrag[dc], cc, 0, 0, 0);
            }
            s[nt] = cc;
        }
        __builtin_amdgcn_s_setprio(0);

        // ---- causal mask: tiles kt = 2qt, 2qt+1 overlap the diagonal ----
        if (causal && (kt >> 1) == qt) {
            const int kofs = kt * 64 - qt * 128 - wave * 16;  // k_local - q base
#pragma unroll
            for (int nt = 0; nt < 4; nt++)
#pragma unroll
                for (int reg = 0; reg < 4; reg++)
                    if (kofs + nt * 16 + lhi * 4 + reg > l15)
                        s[nt][reg] = -INFINITY;
        }

        // ---- in-register online softmax with defer-max (THR=8, log2) ----
        // max tree in v_max3-fusable triples (T17)
        float a0 = fmaxf(fmaxf(s[0][0], s[0][1]), s[0][2]);
        float a1 = fmaxf(fmaxf(s[0][3], s[1][0]), s[1][1]);
        float a2 = fmaxf(fmaxf(s[1][2], s[1][3]), s[2][0]);
        float a3 = fmaxf(fmaxf(s[2][1], s[2][2]), s[2][3]);
        float a4 = fmaxf(fmaxf(s[3][0], s[3][1]), s[3][2]);
        float b0 = fmaxf(fmaxf(a0, a1), a2);
        float b1 = fmaxf(fmaxf(a3, a4), s[3][3]);
        float mt = fmaxf(b0, b1);
        mt = fmaxf(mt, __shfl_xor(mt, 16));
        mt = fmaxf(mt, __shfl_xor(mt, 32));
        if (!__all(mt - m_run <= 8.0f)) {
            float mn = fmaxf(m_run, mt);
            float sc = exp2f(m_run - mn);
            l_run *= sc;                        // row-uniform sc: per-lane safe
            float scr[4];
#pragma unroll
            for (int reg = 0; reg < 4; reg++) scr[reg] = __shfl(sc, lhi * 4 + reg);
#pragma unroll
            for (int dt = 0; dt < 4; dt++)
#pragma unroll
                for (int reg = 0; reg < 4; reg++) acc[dt][reg] *= scr[reg];
            m_run = mn;
        }
        // exp + per-lane partial sum (cross-lane reduce deferred to epilogue)
        float psn[4];
#pragma unroll
        for (int nt = 0; nt < 4; nt++) {
            float p0 = exp2f(s[nt][0] - m_run);
            float p1 = exp2f(s[nt][1] - m_run);
            float p2 = exp2f(s[nt][2] - m_run);
            float p3 = exp2f(s[nt][3] - m_run);
            s[nt][0] = p0; s[nt][1] = p1; s[nt][2] = p2; s[nt][3] = p3;
            psn[nt] = (p0 + p1) + (p2 + p3);
        }
        l_run += (psn[0] + psn[1]) + (psn[2] + psn[3]);

        // ---- P -> wave-private LDS bridge: 4 consecutive k per write ----
        char* pl = (char*)P_lds[wave];
        const int rs = (l15 & 7) << 4;
#pragma unroll
        for (int nt = 0; nt < 4; nt++) {
            bf16x4 pw;
#pragma unroll
            for (int reg = 0; reg < 4; reg++) pw[reg] = (__bf16)s[nt][reg];
            *(bf16x4*)(pl + ((l15 * 128 + (nt * 16 + lhi * 4) * 2) ^ rs)) = pw;
        }

        // ---- O += P V ----
        __builtin_amdgcn_s_setprio(1);
#pragma unroll
        for (int kc = 0; kc < 2; kc++) {
            const bf16x8 pfg = *(const bf16x8*)(pl +
                ((l15 * 128 + kc * 64 + lhi * 16) ^ rs));
#pragma unroll
            for (int dt = 0; dt < 4; dt++) {
                int drow = dt * 16 + l15;
                const bf16x8 vf = *(const bf16x8*)(Vb +
                    ((drow * 128 + kc * 64 + lhi * 16) ^ VSWZ(drow)));
                acc[dt] = __builtin_amdgcn_mfma_f32_16x16x32_bf16(pfg, vf, acc[dt], 0, 0, 0);
            }
        }
        __builtin_amdgcn_s_setprio(0);

        __syncthreads();                       // all reads of KV done
        if (pf) {
            STORE_TILE();                      // overwrite with tile kt+1
            __syncthreads();                   // staged
        }
    }

    // ---- deferred l-reduction (once per block, was once per tile) ----
    l_run += __shfl_xor(l_run, 16);
    l_run += __shfl_xor(l_run, 32);

    if (direct) {
        // ---- normalize + scatter + fused zero rows ----
        float lq[4];
#pragma unroll
        for (int reg = 0; reg < 4; reg++) lq[reg] = __shfl(l_run, lhi * 4 + reg);
#pragma unroll
        for (int reg = 0; reg < 4; reg++) {
            float inv = 1.0f / lq[reg];
            int qr = qrow_base + lhi * 4 + reg;
            long tok = sstart + off + (long)r * qr;
            float* op = Og + tok * 768 + head * 64 + l15;
#pragma unroll
            for (int dt = 0; dt < 4; dt++) op[dt * 16] = acc[dt][reg] * inv;
            if (r >= 2) {
                float* z1 = op - 768;
#pragma unroll
                for (int dt = 0; dt < 4; dt++) z1[dt * 16] = 0.f;
            }
            if (r == 4) {
                float* z2 = op - 2 * 768;
                float* z3 = op + 768;
#pragma unroll
                for (int dt = 0; dt < 4; dt++) { z2[dt * 16] = 0.f; z3[dt * 16] = 0.f; }
            }
        }
    } else {
        // ---- write unnormalized partial to ws slot (bf16 O, f32 m/l) ----
        const int b = (qt < 12) ? (qt - 8) * 3 : 12 + (qt - 12) * 4;
        char* slotp = ws + (size_t)(inst * 28 + b + c) * 17408;
        __bf16* so = (__bf16*)slotp;
#pragma unroll
        for (int reg = 0; reg < 4; reg++) {
            int row = wave * 16 + lhi * 4 + reg;
#pragma unroll
            for (int dt = 0; dt < 4; dt++)
                so[row * 64 + dt * 16 + l15] = (__bf16)acc[dt][reg];
        }
        if (lhi == 0) {                         // lane owns q = l15
            float* ml = (float*)(slotp + 16384);
            ml[wave * 16 + l15]       = m_run;
            ml[128 + wave * 16 + l15] = l_run;
        }
    }
#undef LOAD_STEP
#undef STORE_TILE
}

// 4-way row-split merge: 28 insts x 8 qt (8..15) x 4 quarters = 896 blocks.
// Each thread owns (row, 8-float strip): coalesced bf16x8 reads.
__global__ __launch_bounds__(256)
void dilattn_merge(const char* __restrict__ ws, float* __restrict__ Og,
                   const int* __restrict__ causal_p)
{
    if (!*causal_p) return;                    // non-causal handled directly
    const int bid  = blockIdx.x;
    const int inst = bid / 32;
    const int rem  = bid % 32;
    const int qt   = 8 + (rem >> 2);           // 8..15
    const int quarter = rem & 3;
    int head, sstart, r, off;
    inst_decode(inst, head, sstart, r, off);

    const int nc = (qt < 12) ? 3 : 4;          // chunks
    const int b  = (qt < 12) ? (qt - 8) * 3 : 12 + (qt - 12) * 4;
    const char* base = ws + (size_t)(inst * 28 + b) * 17408;

    const int tid = threadIdx.x;
    const int row = quarter * 32 + (tid >> 3); // 0..127
    const int c8  = (tid & 7) * 8;

    float mv[4], lv[4];
    float m = -INFINITY;
#pragma unroll
    for (int c = 0; c < 4; c++) {
        if (c < nc) {
            const float* ml = (const float*)(base + c * 17408 + 16384);
            mv[c] = ml[row];
            lv[c] = ml[128 + row];
            m = fmaxf(m, mv[c]);
        }
    }
    float w[4];
    float L = 0.f;
#pragma unroll
    for (int c = 0; c < 4; c++) {
        if (c < nc) {
            w[c] = exp2f(mv[c] - m);
            L += w[c] * lv[c];
        }
    }
    const float invL = 1.0f / L;

    float o[8] = {};
#pragma unroll
    for (int c = 0; c < 4; c++) {
        if (c < nc) {
            const __bf16* ob = (const __bf16*)(base + c * 17408) + row * 64 + c8;
            bf16x8 t = *(const bf16x8*)ob;
#pragma unroll
            for (int e = 0; e < 8; e++) o[e] += w[c] * (float)t[e];
        }
    }

    long tok = sstart + off + (long)r * (qt * 128 + row);
    float* og = Og + tok * 768 + head * 64 + c8;
    f32x4 t0, t1;
#pragma unroll
    for (int e = 0; e < 4; e++) { t0[e] = o[e] * invL; t1[e] = o[4 + e] * invL; }
    *(f32x4*)(og)     = t0;
    *(f32x4*)(og + 4) = t1;

    // ---- fused zero rows for non-dilated tokens ----
    const f32x4 zz = {};
    if (r >= 2) {
        float* z1 = og - 768;
        *(f32x4*)(z1) = zz; *(f32x4*)(z1 + 4) = zz;
    }
    if (r == 4) {
        float* z2 = og - 2 * 768;
        float* z3 = og + 768;
        *(f32x4*)(z2) = zz; *(f32x4*)(z2 + 4) = zz;
        *(f32x4*)(z3) = zz; *(f32x4*)(z3 + 4) = zz;
    }
}

extern "C" void kernel_launch(void* const* d_in, const int* in_sizes, int n_in,
                              void* d_out, int out_size, void* d_ws, size_t ws_size,
                              hipStream_t stream)
{
    const float* q = (const float*)d_in[0];
    const float* k = (const float*)d_in[1];
    const float* v = (const float*)d_in[2];
    const int* causal = (const int*)d_in[3];
    float* out = (float*)d_out;
    char* ws   = (char*)d_ws;

    dilattn_partial<<<dim3(28 * 36), dim3(512), 0, stream>>>(q, k, v, out, ws, causal);
    dilattn_merge<<<dim3(28 * 32), dim3(256), 0, stream>>>(ws, out, causal);
}

// Round 15
// 59.231 us; speedup vs baseline: 1.1109x; 1.1109x over previous
//
#include <hip/hip_runtime.h>

typedef __attribute__((ext_vector_type(8))) __bf16 bf16x8;
typedef __attribute__((ext_vector_type(4))) __bf16 bf16x4;
typedef __attribute__((ext_vector_type(2))) __bf16 bf16x2;
typedef __attribute__((ext_vector_type(4))) float f32x4;

#define LOG2E 1.44269504088896f
#define KSWZ(t) (((t) & 7) << 4)
#define VSWZ(d) ((((d) & 7) ^ (((d) >> 3) & 7)) << 4)

// 28 instances of dilated causal attention, each L=2048, d=64.
// q/k/v: (1, 8192, 12, 64) fp32 -> elem = tok*768 + head*64 + d.
// PARTIAL = R13 decomposition (proven best): QBLK=128 (8 waves x 16 q-rows),
// qt in 0..15, nkt = 2qt+2 KV tiles of 64, chunks <=8 tiles: 40 units/inst
// (4 direct qt<4 + 8 + 12 + 16) -> 1120 balanced blocks, XCD-chunked,
// heavy-first. R14 lesson: do NOT widen direct range — 16-tile serial poles
// set the makespan (62 us vs 56). Wave-specialized staging (w0-3: K,
// w4-7: V^T), swapped QK^T, in-register softmax, defer-max THR=8,
// v_max3 tree, strength-reduced staging pointers.
// R15: DEFERRED l-reduce — per-tile cross-lane sum removed (2 ds_swizzle +
// 2 adds per wave-tile); single shfl-pair in epilogue. Row-uniform rescale
// (mt reduced over xor16/32 before compare) makes per-lane partial l exact.
// HARD CONSTRAINTS: VGPR <= 64 (R10); decode/nkt/mask/slot ONE COUPLED UNIT.
// Two kernels, NO device fences (R7). Zero-rows fused (no memset).
// ws slot (17408 B): O[128][64] bf16 + m[128] f32 + l[128] f32.
// slot = inst*36 + b + c,  b = (qt<8)?(qt-4)*2 : (qt<12)?8+(qt-8)*3
//                                              : 20+(qt-12)*4.

__device__ __forceinline__ void inst_decode(int inst, int& head, int& sstart,
                                            int& r, int& off)
{
    if (inst < 16)      { head = inst & 3;          sstart = (inst >> 2) * 2048; r = 1; off = 0; }
    else if (inst < 24) { int j = inst - 16; head = 4 + (j & 3); sstart = (j >> 2) * 4096; r = 2; off = 1; }
    else                { head = 8 + (inst - 24);   sstart = 0;                  r = 4; off = 2; }
}

__global__ __launch_bounds__(512)
void dilattn_partial(const float* __restrict__ Qg, const float* __restrict__ Kg,
                     const float* __restrict__ Vg, float* __restrict__ Og,
                     char* __restrict__ ws, const int* __restrict__ causal_p)
{
    const int bid  = blockIdx.x;
    const int unit = (bid & 7) * 140 + (bid >> 3);   // XCD-contiguous units
    const int inst = unit / 40;
    const int u    = 39 - (unit % 40);               // heavy chunks first
    int qt, c;
    if (u < 4) { qt = u; c = 0; }
    else {
        int v = u - 4;
        if (v < 8)       { qt = 4 + (v >> 1); c = v & 1; }
        else if (v < 20) { int t = v - 8; int q3 = t / 3; qt = 8 + q3; c = t - 3 * q3; }
        else             { int t = v - 20; qt = 12 + (t >> 2); c = t & 3; }
    }
    int head, sstart, r, off;
    inst_decode(inst, head, sstart, r, off);

    const int causal = *causal_p;
    int kt_begin, kt_end;
    bool direct;
    if (causal) {
        int nkt = 2 * qt + 2;
        kt_begin = c * 8;
        kt_end   = (kt_begin + 8 < nkt) ? kt_begin + 8 : nkt;
        direct   = (qt < 4);
    } else {
        if (c) return;
        kt_begin = 0; kt_end = 32; direct = true;
    }

    const int tid  = threadIdx.x;
    const int lane = tid & 63;
    const int wave = tid >> 6;                 // 0..7
    const int l15  = lane & 15;
    const int lhi  = lane >> 4;

    __shared__ char KV[16384];                 // K 8K | V^T 8K (single buffer)
    __shared__ __bf16 P_lds[8][16 * 64];       // per-wave P bridge (swizzled)

    // ---- Q fragments (scale * log2e folded in); serves as MFMA B ----
    const int qrow_base = qt * 128 + wave * 16;
    const float qscale = 0.125f * LOG2E;
    bf16x8 qfrag[2];
    {
        int qr = qrow_base + l15;
        long qtok = sstart + off + (long)r * qr;
        const float* qp = Qg + qtok * 768 + head * 64 + lhi * 8;
#pragma unroll
        for (int dc = 0; dc < 2; dc++) {
            f32x4 a = *(const f32x4*)(qp + dc * 32);
            f32x4 b = *(const f32x4*)(qp + dc * 32 + 4);
#pragma unroll
            for (int j = 0; j < 4; j++) {
                qfrag[dc][j]     = (__bf16)(a[j] * qscale);
                qfrag[dc][4 + j] = (__bf16)(b[j] * qscale);
            }
        }
    }

    f32x4 acc[4] = {};                          // O: row q=lhi*4+reg, col d=dt*16+l15
    float m_run = -INFINITY;                    // per-lane: q = l15
    float l_run = 0.f;                          // per-lane PARTIAL (reduced at end)

    // ---- wave-specialized staging roles ----
    const bool isK = (wave < 4);
    const int t2   = tid & 255;
    const int tokK = t2 >> 2, q4 = t2 & 3;          // K: (token, d-quarter)
    const int tokP = t2 >> 3, d8 = (t2 & 7) * 8;    // V: (token-pair, 8 d)

    f32x4 r0, r1, r2, r3;                       // staging regs (next tile)

    // ---- strength-reduced staging pointer: advance by one tile-stride ----
    const long gstep = (long)r * 64 * 768;      // floats per KV tile step
    const long vrow  = (long)r * 768;           // one dilated token (floats)
    const float* gp0;
    {
        long tb = sstart + off + (long)r * (kt_begin * 64);
        gp0 = isK ? (Kg + (tb + (long)r * tokK) * 768 + head * 64 + q4 * 16)
                  : (Vg + (tb + (long)r * 2 * tokP) * 768 + head * 64 + d8);
    }

#define LOAD_STEP() do {                                                       \
        if (isK) {                                                             \
            r0 = *(const f32x4*)(gp0);      r1 = *(const f32x4*)(gp0 + 4);     \
            r2 = *(const f32x4*)(gp0 + 8);  r3 = *(const f32x4*)(gp0 + 12);    \
        } else {                                                               \
            const float* g1_ = gp0 + vrow;                                     \
            r0 = *(const f32x4*)(gp0);      r1 = *(const f32x4*)(gp0 + 4);     \
            r2 = *(const f32x4*)(g1_);      r3 = *(const f32x4*)(g1_ + 4);     \
        }                                                                      \
        gp0 += gstep;                                                          \
    } while (0)

#define STORE_TILE() do {                                                      \
        if (isK) {                                                             \
            char* Kb_ = KV;                                                    \
            bf16x8 w0_, w1_;                                                   \
            _Pragma("unroll")                                                  \
            for (int j = 0; j < 4; j++) {                                      \
                w0_[j] = (__bf16)r0[j]; w0_[4 + j] = (__bf16)r1[j];            \
                w1_[j] = (__bf16)r2[j]; w1_[4 + j] = (__bf16)r3[j];            \
            }                                                                  \
            int kb_ = tokK * 128 + q4 * 32;                                    \
            *(bf16x8*)(Kb_ + ((kb_)      ^ KSWZ(tokK))) = w0_;                 \
            *(bf16x8*)(Kb_ + ((kb_ + 16) ^ KSWZ(tokK))) = w1_;                 \
        } else {                                                               \
            char* Vb_ = KV + 8192;                                             \
            _Pragma("unroll")                                                  \
            for (int j = 0; j < 4; j++) {                                      \
                int d_ = d8 + j;                                               \
                bf16x2 wa_; wa_[0] = (__bf16)r0[j]; wa_[1] = (__bf16)r2[j];    \
                *(bf16x2*)(Vb_ + ((d_ * 128 + tokP * 4) ^ VSWZ(d_))) = wa_;    \
                int d2_ = d8 + 4 + j;                                          \
                bf16x2 wb_; wb_[0] = (__bf16)r1[j]; wb_[1] = (__bf16)r3[j];    \
                *(bf16x2*)(Vb_ + ((d2_ * 128 + tokP * 4) ^ VSWZ(d2_))) = wb_;  \
            }                                                                  \
        }                                                                      \
    } while (0)

    // ---- prologue: stage first tile ----
    LOAD_STEP();
    STORE_TILE();
    __syncthreads();

    for (int kt = kt_begin; kt < kt_end; kt++) {
        const bool pf = (kt + 1 < kt_end);
        if (pf) LOAD_STEP();                   // tile kt+1; lands under compute

        char* Kb = KV;
        char* Vb = KV + 8192;

        // ---- S' = K Q^T : lane owns q = l15; regs (nt,reg) = k values ----
        f32x4 s[4];
        __builtin_amdgcn_s_setprio(1);
#pragma unroll
        for (int nt = 0; nt < 4; nt++) {
            f32x4 cc = {};
#pragma unroll
            for (int dc = 0; dc < 2; dc++) {
                int krow = nt * 16 + l15;
                const bf16x8 kf = *(const bf16x8*)(Kb +
                    ((krow * 128 + dc * 64 + lhi * 16) ^ KSWZ(krow)));
                cc = __builtin_amdgcn_mfma_f32_16x16x32_bf16(kf, qfrag[dc], cc, 0, 0, 0);
            }
            s[nt] = cc;
        }
        __builtin_amdgcn_s_setprio(0);

        // ---- causal mask: tiles kt = 2qt, 2qt+1 overlap the diagonal ----
        if (causal && (kt >> 1) == qt) {
            const int kofs = kt * 64 - qt * 128 - wave * 16;  // k_local - q base
#pragma unroll
            for (int nt = 0; nt < 4; nt++)
#pragma unroll
                for (int reg = 0; reg < 4; reg++)
                    if (kofs + nt * 16 + lhi * 4 + reg > l15)
                        s[nt][reg] = -INFINITY;
        }

        // ---- in-register online softmax with defer-max (THR=8, log2) ----
        // max tree in v_max3-fusable triples (T17)
        float a0 = fmaxf(fmaxf(s[0][0], s[0][1]), s[0][2]);
        float a1 = fmaxf(fmaxf(s[0][3], s[1][0]), s[1][1]);
        float a2 = fmaxf(fmaxf(s[1][2], s[1][3]), s[2][0]);
        float a3 = fmaxf(fmaxf(s[2][1], s[2][2]), s[2][3]);
        float a4 = fmaxf(fmaxf(s[3][0], s[3][1]), s[3][2]);
        float b0 = fmaxf(fmaxf(a0, a1), a2);
        float b1 = fmaxf(fmaxf(a3, a4), s[3][3]);
        float mt = fmaxf(b0, b1);
        mt = fmaxf(mt, __shfl_xor(mt, 16));
        mt = fmaxf(mt, __shfl_xor(mt, 32));
        if (!__all(mt - m_run <= 8.0f)) {
            float mn = fmaxf(m_run, mt);
            float sc = exp2f(m_run - mn);
            l_run *= sc;                        // row-uniform sc: per-lane safe
            float scr[4];
#pragma unroll
            for (int reg = 0; reg < 4; reg++) scr[reg] = __shfl(sc, lhi * 4 + reg);
#pragma unroll
            for (int dt = 0; dt < 4; dt++)
#pragma unroll
                for (int reg = 0; reg < 4; reg++) acc[dt][reg] *= scr[reg];
            m_run = mn;
        }
        // exp + per-lane partial sum (cross-lane reduce deferred to epilogue)
        float psn[4];
#pragma unroll
        for (int nt = 0; nt < 4; nt++) {
            float p0 = exp2f(s[nt][0] - m_run);
            float p1 = exp2f(s[nt][1] - m_run);
            float p2 = exp2f(s[nt][2] - m_run);
            float p3 = exp2f(s[nt][3] - m_run);
            s[nt][0] = p0; s[nt][1] = p1; s[nt][2] = p2; s[nt][3] = p3;
            psn[nt] = (p0 + p1) + (p2 + p3);
        }
        l_run += (psn[0] + psn[1]) + (psn[2] + psn[3]);

        // ---- P -> wave-private LDS bridge: 4 consecutive k per write ----
        char* pl = (char*)P_lds[wave];
        const int rs = (l15 & 7) << 4;
#pragma unroll
        for (int nt = 0; nt < 4; nt++) {
            bf16x4 pw;
#pragma unroll
            for (int reg = 0; reg < 4; reg++) pw[reg] = (__bf16)s[nt][reg];
            *(bf16x4*)(pl + ((l15 * 128 + (nt * 16 + lhi * 4) * 2) ^ rs)) = pw;
        }

        // ---- O += P V ----
        __builtin_amdgcn_s_setprio(1);
#pragma unroll
        for (int kc = 0; kc < 2; kc++) {
            const bf16x8 pfg = *(const bf16x8*)(pl +
                ((l15 * 128 + kc * 64 + lhi * 16) ^ rs));
#pragma unroll
            for (int dt = 0; dt < 4; dt++) {
                int drow = dt * 16 + l15;
                const bf16x8 vf = *(const bf16x8*)(Vb +
                    ((drow * 128 + kc * 64 + lhi * 16) ^ VSWZ(drow)));
                acc[dt] = __builtin_amdgcn_mfma_f32_16x16x32_bf16(pfg, vf, acc[dt], 0, 0, 0);
            }
        }
        __builtin_amdgcn_s_setprio(0);

        __syncthreads();                       // all reads of KV done
        if (pf) {
            STORE_TILE();                      // overwrite with tile kt+1
            __syncthreads();                   // staged
        }
    }

    // ---- deferred l-reduction (once per block, was once per tile) ----
    l_run += __shfl_xor(l_run, 16);
    l_run += __shfl_xor(l_run, 32);

    if (direct) {
        // ---- normalize + scatter + fused zero rows ----
        float lq[4];
#pragma unroll
        for (int reg = 0; reg < 4; reg++) lq[reg] = __shfl(l_run, lhi * 4 + reg);
#pragma unroll
        for (int reg = 0; reg < 4; reg++) {
            float inv = 1.0f / lq[reg];
            int qr = qrow_base + lhi * 4 + reg;
            long tok = sstart + off + (long)r * qr;
            float* op = Og + tok * 768 + head * 64 + l15;
#pragma unroll
            for (int dt = 0; dt < 4; dt++) op[dt * 16] = acc[dt][reg] * inv;
            if (r >= 2) {
                float* z1 = op - 768;
#pragma unroll
                for (int dt = 0; dt < 4; dt++) z1[dt * 16] = 0.f;
            }
            if (r == 4) {
                float* z2 = op - 2 * 768;
                float* z3 = op + 768;
#pragma unroll
                for (int dt = 0; dt < 4; dt++) { z2[dt * 16] = 0.f; z3[dt * 16] = 0.f; }
            }
        }
    } else {
        // ---- write unnormalized partial to ws slot (bf16 O, f32 m/l) ----
        const int b  = (qt < 8)  ? (qt - 4) * 2
                     : (qt < 12) ? 8 + (qt - 8) * 3
                     :             20 + (qt - 12) * 4;
        char* slotp = ws + (size_t)(inst * 36 + b + c) * 17408;
        __bf16* so = (__bf16*)slotp;
#pragma unroll
        for (int reg = 0; reg < 4; reg++) {
            int row = wave * 16 + lhi * 4 + reg;
#pragma unroll
            for (int dt = 0; dt < 4; dt++)
                so[row * 64 + dt * 16 + l15] = (__bf16)acc[dt][reg];
        }
        if (lhi == 0) {                         // lane owns q = l15
            float* ml = (float*)(slotp + 16384);
            ml[wave * 16 + l15]       = m_run;
            ml[128 + wave * 16 + l15] = l_run;
        }
    }
#undef LOAD_STEP
#undef STORE_TILE
}

// 4-way row-split merge: 28 insts x 12 qt x 4 quarters = 1344 blocks.
// Each thread owns (row, 8-float strip): coalesced bf16x8 reads.
__global__ __launch_bounds__(256)
void dilattn_merge(const char* __restrict__ ws, float* __restrict__ Og,
                   const int* __restrict__ causal_p)
{
    if (!*causal_p) return;                    // non-causal handled directly
    const int bid  = blockIdx.x;
    const int inst = bid / 48;
    const int rem  = bid % 48;
    const int qt   = 4 + (rem >> 2);           // 4..15
    const int quarter = rem & 3;
    int head, sstart, r, off;
    inst_decode(inst, head, sstart, r, off);

    const int nc = (2 * qt + 9) >> 3;          // chunks: 2..4
    const int b  = (qt < 8)  ? (qt - 4) * 2
                 : (qt < 12) ? 8 + (qt - 8) * 3
                 :             20 + (qt - 12) * 4;
    const char* base = ws + (size_t)(inst * 36 + b) * 17408;

    const int tid = threadIdx.x;
    const int row = quarter * 32 + (tid >> 3); // 0..127
    const int c8  = (tid & 7) * 8;

    float mv[4], lv[4];
    float m = -INFINITY;
#pragma unroll
    for (int c = 0; c < 4; c++) {
        if (c < nc) {
            const float* ml = (const float*)(base + c * 17408 + 16384);
            mv[c] = ml[row];
            lv[c] = ml[128 + row];
            m = fmaxf(m, mv[c]);
        }
    }
    float w[4];
    float L = 0.f;
#pragma unroll
    for (int c = 0; c < 4; c++) {
        if (c < nc) {
            w[c] = exp2f(mv[c] - m);
            L += w[c] * lv[c];
        }
    }
    const float invL = 1.0f / L;

    float o[8] = {};
#pragma unroll
    for (int c = 0; c < 4; c++) {
        if (c < nc) {
            const __bf16* ob = (const __bf16*)(base + c * 17408) + row * 64 + c8;
            bf16x8 t = *(const bf16x8*)ob;
#pragma unroll
            for (int e = 0; e < 8; e++) o[e] += w[c] * (float)t[e];
        }
    }

    long tok = sstart + off + (long)r * (qt * 128 + row);
    float* og = Og + tok * 768 + head * 64 + c8;
    f32x4 t0, t1;
#pragma unroll
    for (int e = 0; e < 4; e++) { t0[e] = o[e] * invL; t1[e] = o[4 + e] * invL; }
    *(f32x4*)(og)     = t0;
    *(f32x4*)(og + 4) = t1;

    // ---- fused zero rows for non-dilated tokens ----
    const f32x4 zz = {};
    if (r >= 2) {
        float* z1 = og - 768;
        *(f32x4*)(z1) = zz; *(f32x4*)(z1 + 4) = zz;
    }
    if (r == 4) {
        float* z2 = og - 2 * 768;
        float* z3 = og + 768;
        *(f32x4*)(z2) = zz; *(f32x4*)(z2 + 4) = zz;
        *(f32x4*)(z3) = zz; *(f32x4*)(z3 + 4) = zz;
    }
}

extern "C" void kernel_launch(void* const* d_in, const int* in_sizes, int n_in,
                              void* d_out, int out_size, void* d_ws, size_t ws_size,
                              hipStream_t stream)
{
    const float* q = (const float*)d_in[0];
    const float* k = (const float*)d_in[1];
    const float* v = (const float*)d_in[2];
    const int* causal = (const int*)d_in[3];
    float* out = (float*)d_out;
    char* ws   = (char*)d_ws;

    dilattn_partial<<<dim3(28 * 40), dim3(512), 0, stream>>>(q, k, v, out, ws, causal);
    dilattn_merge<<<dim3(28 * 48), dim3(256), 0, stream>>>(ws, out, causal);
}